// Round 21
// baseline (75.353 us; speedup 1.0000x reference)
//
#include <hip/hip_runtime.h>
#include <math.h>

#define NPTS 16384
#define NH   32
#define NC   128
#define NK   43

typedef __attribute__((ext_vector_type(8))) short short8;
typedef __attribute__((ext_vector_type(4))) float f32x4;

// ---------------- workspace layout (float indices) ----------------
enum : int {
  OFF_SC1  = 0,   OFF_SH1 = 128,
  OFF_SC2  = 256, OFF_SH2 = 384,
  OFF_SC3  = 512, OFF_SH3 = 640,
  OFF_RED  = 768,       // 32*256 second-level partials
  OFF_CNT  = 8960,      // arrival counter (1 uint) + pad
  OFF_PART = 9216,      // up to 2048*256 f32 partials (all 3 BN stages)
  OFF_A    = 1057792,   // N*C floats
  OFF_B    = 1057792 + NPTS*NC,
};
// F (packed bf16 features, 4 MB) lives in d_out's feat section (dead until end).

struct KPArgs { float p[NK * 3]; };

// =================== host-side kernel-point computation ===================
static void host_make_kp(float* kp) {
  unsigned int mt[624];
  mt[0] = 42u;
  for (int i = 1; i < 624; ++i)
    mt[i] = 1812433253u * (mt[i-1] ^ (mt[i-1] >> 30)) + (unsigned)i;
  int pos = 624;
  auto next = [&]() -> unsigned int {
    if (pos == 624) {
      for (int i = 0; i < 624; ++i) {
        unsigned int y = (mt[i] & 0x80000000u) | (mt[(i+1)%624] & 0x7fffffffu);
        unsigned int v = mt[(i+397)%624] ^ (y >> 1);
        if (y & 1u) v ^= 0x9908b0dfu;
        mt[i] = v;
      }
      pos = 0;
    }
    unsigned int y = mt[pos++];
    y ^= y >> 11;
    y ^= (y << 7)  & 0x9d2c5680u;
    y ^= (y << 15) & 0xefc60000u;
    y ^= y >> 18;
    return y;
  };
  auto rdouble = [&]() -> double {
    unsigned int a = next() >> 5, b = next() >> 6;
    return ((double)a * 67108864.0 + (double)b) / 9007199254740992.0;
  };
  double gcache = 0.0; bool has_g = false;
  auto gauss = [&]() -> double {
    if (has_g) { has_g = false; return gcache; }
    double x1, x2, r2;
    do {
      x1 = 2.0 * rdouble() - 1.0;
      x2 = 2.0 * rdouble() - 1.0;
      r2 = x1*x1 + x2*x2;
    } while (r2 >= 1.0 || r2 == 0.0);
    double f = sqrt(-2.0 * log(r2) / r2);
    gcache = f * x1; has_g = true;
    return f * x2;
  };
  double g[126];
  for (int i = 0; i < 126; ++i) g[i] = gauss();
  kp[0] = 0.f; kp[1] = 0.f; kp[2] = 0.f;
  for (int r = 0; r < 14; ++r) {
    double x = g[r*3], y = g[r*3+1], z = g[r*3+2];
    double nrm = sqrt(x*x + y*y + z*z);
    kp[(1+r)*3+0] = (float)(x / nrm * 0.5);
    kp[(1+r)*3+1] = (float)(y / nrm * 0.5);
    kp[(1+r)*3+2] = (float)(z / nrm * 0.5);
  }
  for (int r = 0; r < 28; ++r) {
    double x = g[42+r*3], y = g[42+r*3+1], z = g[42+r*3+2];
    double nrm = sqrt(x*x + y*y + z*z);
    kp[(15+r)*3+0] = (float)(x / nrm);
    kp[(15+r)*3+1] = (float)(y / nrm);
    kp[(15+r)*3+2] = (float)(z / nrm);
  }
}

__device__ __forceinline__ unsigned short f2bf(float f) {   // RNE
  unsigned u = __float_as_uint(f);
  return (unsigned short)((u + 0x7FFFu + ((u >> 16) & 1u)) >> 16);
}
__device__ __forceinline__ unsigned pack_bf_trunc(float a, float b) {
  return __builtin_amdgcn_perm(__float_as_uint(b), __float_as_uint(a), 0x07060302);
}

// ==== MFMA GEMM: 4 waves/block, W packed from raw into LDS in-kernel ======
// BN=input-BN+ReLU, PACK=write bf16-pair F, NSP=N-split
template<int BN, int PACK, int NSP>
__global__ __launch_bounds__(256) void gemm_mfma(
    const float* __restrict__ A, const float* __restrict__ Wraw,
    const float* __restrict__ sc, const float* __restrict__ sh,
    float* __restrict__ out, unsigned* __restrict__ Fpk,
    float* __restrict__ part, unsigned* __restrict__ cnt) {
  constexpr int NFRAG = 32 / NSP;
  __shared__ uint4 w_l[NFRAG * 64];
  int tid = threadIdx.x;
  int half = (NSP == 1) ? 0 : (blockIdx.x & 1);
  if (PACK && blockIdx.x == 0 && tid == 0) *cnt = 0u;   // first-use counter init

  // pack W B-frags straight from raw row-major [c][k] f32 into LDS
  #pragma unroll
  for (int i = 0; i < NFRAG*64/256; ++i) {
    int s = i*256 + tid;
    int lf = s >> 6, l2 = s & 63;
    int gf = (NSP == 1) ? lf : (half*16 + lf);
    int nt = gf >> 2, ks = gf & 3;
    int c = nt*16 + (l2 & 15), k0 = ks*32 + ((l2 >> 4) << 3);
    const float* p = Wraw + (size_t)c * NC + k0;
    float4 a0 = *(const float4*)(p);
    float4 a1 = *(const float4*)(p + 4);
    uint4 q;
    q.x = (unsigned)f2bf(a0.x) | ((unsigned)f2bf(a0.y) << 16);
    q.y = (unsigned)f2bf(a0.z) | ((unsigned)f2bf(a0.w) << 16);
    q.z = (unsigned)f2bf(a1.x) | ((unsigned)f2bf(a1.y) << 16);
    q.w = (unsigned)f2bf(a1.z) | ((unsigned)f2bf(a1.w) << 16);
    w_l[s] = q;
  }
  __syncthreads();

  int l = tid & 63, wv = tid >> 6;
  int li = l & 15, g = l >> 4;
  int rt = ((NSP == 1) ? blockIdx.x : (blockIdx.x >> 1)) * 4 + wv;
  const float* arow = A + (size_t)(rt * 16 + li) * NC;

  short8 afr[4];
  #pragma unroll
  for (int ks = 0; ks < 4; ++ks) {
    int k0 = ks*32 + g*8;
    float4 a0 = *(const float4*)(arow + k0);
    float4 a1 = *(const float4*)(arow + k0 + 4);
    float v[8] = {a0.x,a0.y,a0.z,a0.w,a1.x,a1.y,a1.z,a1.w};
    if (BN) {
      float4 s0 = *(const float4*)(sc + k0), s1 = *(const float4*)(sc + k0 + 4);
      float4 h0 = *(const float4*)(sh + k0), h1 = *(const float4*)(sh + k0 + 4);
      float ss[8] = {s0.x,s0.y,s0.z,s0.w,s1.x,s1.y,s1.z,s1.w};
      float hh[8] = {h0.x,h0.y,h0.z,h0.w,h1.x,h1.y,h1.z,h1.w};
      #pragma unroll
      for (int i = 0; i < 8; ++i) v[i] = fmaxf(0.f, fmaf(v[i], ss[i], hh[i]));
    }
    union { unsigned q[4]; short8 s; } pk;
    #pragma unroll
    for (int p = 0; p < 4; ++p) pk.q[p] = pack_bf_trunc(v[2*p], v[2*p+1]);
    afr[ks] = pk.s;
  }

  constexpr int NT = 8 / NSP;
  f32x4 acc[NT];
  #pragma unroll
  for (int nt = 0; nt < NT; ++nt) acc[nt] = (f32x4){0.f,0.f,0.f,0.f};
  #pragma unroll
  for (int nt = 0; nt < NT; ++nt) {
    #pragma unroll
    for (int ks = 0; ks < 4; ++ks) {
      union { uint4 u; short8 s; } b;
      b.u = w_l[(nt*4 + ks)*64 + l];               // LDS (lgkmcnt only)
      acc[nt] = __builtin_amdgcn_mfma_f32_16x16x32_bf16(afr[ks], b.s, acc[nt], 0, 0, 0);
    }
  }

  if (PACK) {
    #pragma unroll
    for (int r = 0; r < 4; ++r) {
      uint4 q;
      q.x = pack_bf_trunc(acc[0][r], acc[4][r]);
      q.y = pack_bf_trunc(acc[1][r], acc[5][r]);
      q.z = pack_bf_trunc(acc[2][r], acc[6][r]);
      q.w = pack_bf_trunc(acc[3][r], acc[7][r]);
      ((uint4*)(Fpk + (size_t)(rt*16 + g*4 + r) * 64))[li] = q;
    }
  } else {
    #pragma unroll
    for (int nt = 0; nt < NT; ++nt)
      #pragma unroll
      for (int r = 0; r < 4; ++r)
        out[(size_t)(rt*16 + g*4 + r) * NC + (half*NT + nt)*16 + li] = acc[nt][r];
  }

  float s[NT], q[NT];
  #pragma unroll
  for (int nt = 0; nt < NT; ++nt) {
    float sv = acc[nt][0]+acc[nt][1]+acc[nt][2]+acc[nt][3];
    float qv = acc[nt][0]*acc[nt][0]+acc[nt][1]*acc[nt][1]
             + acc[nt][2]*acc[nt][2]+acc[nt][3]*acc[nt][3];
    sv += __shfl_xor(sv, 16); sv += __shfl_xor(sv, 32);
    qv += __shfl_xor(qv, 16); qv += __shfl_xor(qv, 32);
    s[nt] = sv; q[nt] = qv;
  }
  if (g == 0) {
    #pragma unroll
    for (int nt = 0; nt < NT; ++nt) {
      int c = (half*NT + nt)*16 + li;
      part[(size_t)rt*256 + c]       = s[nt];
      part[(size_t)rt*256 + 128 + c] = q[nt];
    }
  }
}

// ====== BN finalize: NBLK blocks, last-arriving block combines/finalizes ===
template<int NB, int NBLK>
__global__ __launch_bounds__(256) void bn_final_mb(
    const float* __restrict__ part,
    const float* __restrict__ g, const float* __restrict__ b,
    float* __restrict__ sc, float* __restrict__ sh,
    float* __restrict__ red, unsigned* __restrict__ cnt) {
  int t = threadIdx.x;
  int blk = blockIdx.x;
  constexpr int PER = NB / NBLK;
  size_t base = (size_t)blk * PER * 256 + t;
  float a0 = 0.f, a1 = 0.f, a2 = 0.f, a3 = 0.f;
  for (int i = 0; i < PER; i += 4) {
    a0 += part[base + (size_t)(i+0)*256];
    a1 += part[base + (size_t)(i+1)*256];
    a2 += part[base + (size_t)(i+2)*256];
    a3 += part[base + (size_t)(i+3)*256];
  }
  red[blk*256 + t] = (a0 + a1) + (a2 + a3);
  __threadfence();
  __shared__ unsigned lastv;
  if (t == 0) lastv = atomicAdd(cnt, 1u);
  __syncthreads();
  if (lastv == (unsigned)(NBLK - 1)) {
    __threadfence();
    float S = 0.f;
    #pragma unroll
    for (int k = 0; k < NBLK; ++k) S += red[k*256 + t];
    __shared__ float fs[256];
    fs[t] = S;
    __syncthreads();
    if (t < 128) {
      double mean = (double)fs[t] * (1.0 / (double)NPTS);
      double var  = (double)fs[128+t] * (1.0 / (double)NPTS) - mean * mean;
      double rstd = 1.0 / sqrt(var + 1e-5);
      double scale = (double)g[t] * rstd;
      sc[t] = (float)scale;
      sh[t] = (float)((double)b[t] - mean * scale);
    }
    if (t == 0) *cnt = 0u;
  }
}

// ==== KPConv: 8 pts/block (512 thr), packs cw/kpf in-kernel, c&c acc ======
__global__ __launch_bounds__(512) void kpconv_kernel(
    const float* __restrict__ coord, const int* __restrict__ ref,
    const unsigned* __restrict__ F, const float* __restrict__ cw,
    KPArgs kpa,
    const float* __restrict__ sc1, const float* __restrict__ sh1,
    float* __restrict__ y, float* __restrict__ part)
{
  __shared__ uint4 cw_l[1024];      // all 16 B-frags (16 KB)
  __shared__ float kpf_l[256];
  __shared__ float bnt_l[256];      // sc1[0:128] | sh1[0:128]
  int tid = threadIdx.x;

  // pack conv_w B-frags straight from raw [k][c] f32 (2 slots/thread)
  #pragma unroll
  for (int i = 0; i < 2; ++i) {
    int s = i*512 + tid;            // 0..1023
    int f = s >> 6, l2 = s & 63;
    int ks = f >> 3, nt = f & 7;
    int c = nt*16 + (l2 & 15), k0 = ks*32 + ((l2 >> 4) << 3);
    float v[8];
    #pragma unroll
    for (int ii = 0; ii < 8; ++ii) {
      int k = k0 + ii;
      v[ii] = (k < NK) ? cw[k*NC + c] : 0.f;
    }
    uint4 q;
    q.x = (unsigned)f2bf(v[0]) | ((unsigned)f2bf(v[1]) << 16);
    q.y = (unsigned)f2bf(v[2]) | ((unsigned)f2bf(v[3]) << 16);
    q.z = (unsigned)f2bf(v[4]) | ((unsigned)f2bf(v[5]) << 16);
    q.w = (unsigned)f2bf(v[6]) | ((unsigned)f2bf(v[7]) << 16);
    cw_l[s] = q;
  }
  // kpf table from kernel arg + BN1 tables
  if (tid < 256) {
    int comp = tid >> 6, slot = tid & 63;
    int ks = slot >> 5, gg = (slot >> 3) & 3, ii = slot & 7;
    int k = ks*32 + gg*8 + ii;
    float val;
    if (k < NK) {
      float x = kpa.p[k*3+0], yy = kpa.p[k*3+1], z = kpa.p[k*3+2];
      val = (comp == 0) ? -2.f*x : (comp == 1) ? -2.f*yy : (comp == 2) ? -2.f*z
            : (x*x + yy*yy + z*z);
    } else {
      val = (comp == 3) ? 1e12f : 0.f;
    }
    kpf_l[tid] = val;
    bnt_l[tid] = (tid < 128) ? sc1[tid] : sh1[tid - 128];
  }
  __syncthreads();

  int l = tid & 63, w = tid >> 6;   // wave 0..7, 1 point/wave
  int g = l >> 4, li = l & 15;
  const uint4* F4 = (const uint4*)F;

  int n = blockIdx.x * 8 + w;
  const int* refrow = ref + (size_t)n * NH;

  int jr0 = refrow[li];
  int jr1 = refrow[16 + li];
  int jh0[4], jh1[4];
  #pragma unroll
  for (int r = 0; r < 4; ++r) { jh0[r] = refrow[g*4 + r]; jh1[r] = refrow[16 + g*4 + r]; }

  // coords BEFORE F gathers (vmcnt in-order)
  float cx = coord[n*3+0], cy = coord[n*3+1], cz = coord[n*3+2];
  bool s0r = ((unsigned)jr0 >= (unsigned)NPTS); int j0 = s0r ? 0 : jr0;
  bool s1r = ((unsigned)jr1 >= (unsigned)NPTS); int j1 = s1r ? 0 : jr1;
  float p0x = (s0r ? 1e6f : coord[j0*3+0]) - cx;
  float p0y = (s0r ? 1e6f : coord[j0*3+1]) - cy;
  float p0z = (s0r ? 1e6f : coord[j0*3+2]) - cz;
  float p1x = (s1r ? 1e6f : coord[j1*3+0]) - cx;
  float p1y = (s1r ? 1e6f : coord[j1*3+1]) - cy;
  float p1z = (s1r ? 1e6f : coord[j1*3+2]) - cz;

  // F gathers LAST in the vmcnt queue — in flight through influence + MFMA
  uint4 fqA[4], fqB[4];
  #pragma unroll
  for (int r = 0; r < 4; ++r) {
    int jhc = ((unsigned)jh0[r] >= (unsigned)NPTS) ? 0 : jh0[r];
    fqA[r] = F4[(size_t)jhc * 16 + li];
  }
  #pragma unroll
  for (int r = 0; r < 4; ++r) {
    int jhc = ((unsigned)jh1[r] >= (unsigned)NPTS) ? 0 : jh1[r];
    fqB[r] = F4[(size_t)jhc * 16 + li];
  }

  float pp0 = fmaf(p0z, p0z, fmaf(p0y, p0y, p0x*p0x));
  float pp1 = fmaf(p1z, p1z, fmaf(p1y, p1y, p1x*p1x));

  short8 afr[2][2];   // [mt][ks]
  #pragma unroll
  for (int ks = 0; ks < 2; ++ks) {
    const float* kb = kpf_l + ks*32 + g*8;       // LDS
    float4 X0 = *(const float4*)(kb +   0), X1 = *(const float4*)(kb +   4);
    float4 Y0 = *(const float4*)(kb +  64), Y1 = *(const float4*)(kb +  68);
    float4 Z0 = *(const float4*)(kb + 128), Z1 = *(const float4*)(kb + 132);
    float4 K0 = *(const float4*)(kb + 192), K1 = *(const float4*)(kb + 196);
    float X[8] = {X0.x,X0.y,X0.z,X0.w,X1.x,X1.y,X1.z,X1.w};
    float Y[8] = {Y0.x,Y0.y,Y0.z,Y0.w,Y1.x,Y1.y,Y1.z,Y1.w};
    float Z[8] = {Z0.x,Z0.y,Z0.z,Z0.w,Z1.x,Z1.y,Z1.z,Z1.w};
    float K[8] = {K0.x,K0.y,K0.z,K0.w,K1.x,K1.y,K1.z,K1.w};
    #pragma unroll
    for (int mt = 0; mt < 2; ++mt) {
      float fx = mt ? p1x : p0x, fy = mt ? p1y : p0y, fz = mt ? p1z : p0z;
      float fp = mt ? pp1 : pp0;
      unsigned u[8];
      #pragma unroll
      for (int i = 0; i < 8; ++i) {
        float d2 = fmaf(fz, Z[i], fmaf(fy, Y[i], fmaf(fx, X[i], fp + K[i])));
        d2 = fmaxf(d2, 0.f);
        float iv = fmaxf(1.f - __builtin_amdgcn_sqrtf(d2), 0.f);
        u[i] = __float_as_uint(iv);
      }
      union { unsigned q[4]; short8 s; } pk;
      #pragma unroll
      for (int p = 0; p < 4; ++p)
        pk.q[p] = __builtin_amdgcn_perm(u[2*p+1], u[2*p], 0x07060302);
      afr[mt][ks] = pk.s;
    }
  }

  // BN1 tables from LDS (broadcast reads)
  float s1[8], h1[8];
  #pragma unroll
  for (int p = 0; p < 8; ++p) { s1[p] = bnt_l[p*16 + li]; h1[p] = bnt_l[128 + p*16 + li]; }

  // compute-and-consume accumulators (live acc = one f32x4)
  float outp[8];
  #pragma unroll
  for (int p = 0; p < 8; ++p) outp[p] = 0.f;

  #pragma unroll
  for (int nt = 0; nt < 8; ++nt) {
    union { uint4 u; short8 s; } b0, b1;
    b0.u = cw_l[(0*8 + nt)*64 + l];
    b1.u = cw_l[(1*8 + nt)*64 + l];
    #pragma unroll
    for (int mt = 0; mt < 2; ++mt) {
      f32x4 a = (f32x4){0.f, 0.f, 0.f, 0.f};
      a = __builtin_amdgcn_mfma_f32_16x16x32_bf16(afr[mt][0], b0.s, a, 0, 0, 0);
      a = __builtin_amdgcn_mfma_f32_16x16x32_bf16(afr[mt][1], b1.s, a, 0, 0, 0);
      #pragma unroll
      for (int r = 0; r < 4; ++r) {
        uint4 q = mt ? fqB[r] : fqA[r];
        unsigned uu = (nt & 3) == 0 ? q.x : (nt & 3) == 1 ? q.y
                    : (nt & 3) == 2 ? q.z : q.w;
        float f = (nt < 4) ? __uint_as_float(uu << 16)
                           : __uint_as_float(uu & 0xffff0000u);
        f = fmaxf(0.f, fmaf(f, s1[nt], h1[nt]));
        outp[nt] = fmaf(a[r], f, outp[nt]);
      }
    }
  }

  #pragma unroll
  for (int p = 0; p < 8; ++p) {
    outp[p] += __shfl_xor(outp[p], 16);
    outp[p] += __shfl_xor(outp[p], 32);
  }
  float o0 = (g == 0) ? outp[0] : (g == 1) ? outp[1] : (g == 2) ? outp[2] : outp[3];
  float o1 = (g == 0) ? outp[4] : (g == 1) ? outp[5] : (g == 2) ? outp[6] : outp[7];
  y[(size_t)n * NC + l]      = o0;
  y[(size_t)n * NC + 64 + l] = o1;

  // fused BN2 stats across the block's 8 points
  __shared__ float sl[8][128], ql[8][128];
  sl[w][l] = o0; sl[w][64 + l] = o1;
  ql[w][l] = o0 * o0; ql[w][64 + l] = o1 * o1;
  __syncthreads();
  if (tid < 256) {
    int c = tid & 127;
    const float (*src)[128] = (tid < 128) ? sl : ql;
    float v0 = 0.f, v1 = 0.f;
    #pragma unroll
    for (int k = 0; k < 8; k += 2) { v0 += src[k][c]; v1 += src[k+1][c]; }
    part[(size_t)blockIdx.x*256 + tid] = v0 + v1;
  }
}

// =================== final: out = relu(identity + z*sc + sh) + coord/offset =
__global__ __launch_bounds__(256) void final_out_kernel(
    const float* __restrict__ feat, const float* __restrict__ z,
    const float* __restrict__ sc, const float* __restrict__ sh,
    const float* __restrict__ coord, const int* __restrict__ offs,
    float* __restrict__ out) {
  int i = blockIdx.x * 256 + threadIdx.x;
  if (i < NPTS * NC / 4) {
    float4 f = ((const float4*)feat)[i];
    float4 v = ((const float4*)z)[i];
    int c = (i & 31) << 2;
    v.x = fmaxf(0.f, f.x + fmaf(v.x, sc[c+0], sh[c+0]));
    v.y = fmaxf(0.f, f.y + fmaf(v.y, sc[c+1], sh[c+1]));
    v.z = fmaxf(0.f, f.z + fmaf(v.z, sc[c+2], sh[c+2]));
    v.w = fmaxf(0.f, f.w + fmaf(v.w, sc[c+3], sh[c+3]));
    ((float4*)out)[NPTS*3/4 + i] = v;
  } else {
    int ci = i - NPTS * NC / 4;
    if (ci < NPTS*3/4) ((float4*)out)[ci] = ((const float4*)coord)[ci];
    if (ci == 0) out[NPTS*3 + (size_t)NPTS*NC] = (float)offs[0];
  }
}

// =========================================================================
extern "C" void kernel_launch(void* const* d_in, const int* in_sizes, int n_in,
                              void* d_out, int out_size, void* d_ws, size_t ws_size,
                              hipStream_t stream) {
  (void)in_sizes; (void)n_in; (void)out_size; (void)ws_size;
  const float* coord = (const float*)d_in[0];
  const float* feat  = (const float*)d_in[1];
  const int*   offs  = (const int*)d_in[2];
  const int*   ref   = (const int*)d_in[3];
  const float* w1    = (const float*)d_in[4];
  const float* w3    = (const float*)d_in[5];
  const float* cw    = (const float*)d_in[6];
  const float* g1 = (const float*)d_in[7],  *b1 = (const float*)d_in[8];
  const float* g2 = (const float*)d_in[9],  *b2 = (const float*)d_in[10];
  const float* g3 = (const float*)d_in[11], *b3 = (const float*)d_in[12];

  float* ws  = (float*)d_ws;
  float* out = (float*)d_out;
  float* sc1 = ws + OFF_SC1, *sh1 = ws + OFF_SH1;
  float* sc2 = ws + OFF_SC2, *sh2 = ws + OFF_SH2;
  float* sc3 = ws + OFF_SC3, *sh3 = ws + OFF_SH3;
  float* red  = ws + OFF_RED;
  unsigned* cnt = (unsigned*)(ws + OFF_CNT);
  float* part = ws + OFF_PART;
  float* A = ws + OFF_A;
  float* B = ws + OFF_B;
  unsigned* F = (unsigned*)(out + NPTS*3);

  KPArgs kpa;
  host_make_kp(kpa.p);

  // fc1 (MFMA, packs W1 from raw in-kernel, writes packed F, stats fused)
  gemm_mfma<0,1,1><<<NPTS/64, 256, 0, stream>>>(feat, w1, nullptr, nullptr,
                                                nullptr, F, part, cnt);
  bn_final_mb<1024, 16><<<16, 256, 0, stream>>>(part, g1, b1, sc1, sh1, red, cnt);

  // KPConv (packs cw/kpf in-kernel, BN1 inline, BN2 stats fused)
  kpconv_kernel<<<NPTS/8, 512, 0, stream>>>(coord, ref, F, cw, kpa,
                                            sc1, sh1, B, part);
  bn_final_mb<2048, 32><<<32, 256, 0, stream>>>(part, g2, b2, sc2, sh2, red, cnt);

  // fc3 (MFMA, packs W3-half from raw, BN2-apply fused, stats fused)
  gemm_mfma<1,0,2><<<NPTS/32, 256, 0, stream>>>(B, w3, sc2, sh2, A, nullptr,
                                                part, cnt);
  bn_final_mb<1024, 16><<<16, 256, 0, stream>>>(part, g3, b3, sc3, sh3, red, cnt);

  // residual + ReLU + coord + offset
  final_out_kernel<<<(NPTS*NC/4 + NPTS*3/4 + 255)/256, 256, 0, stream>>>(
      feat, A, sc3, sh3, coord, offs, out);
}

// Round 22
// 72.083 us; speedup vs baseline: 1.0454x; 1.0454x over previous
//
#include <hip/hip_runtime.h>
#include <math.h>

#define NPTS 16384
#define NH   32
#define NC   128
#define NK   43

typedef __attribute__((ext_vector_type(8))) short short8;
typedef __attribute__((ext_vector_type(4))) float f32x4;

// ---------------- workspace layout (float indices) ----------------
enum : int {
  OFF_W1PK = 0,         // 8192  (32 frags x 64 lanes x uint4)
  OFF_W3PK = 8192,      // 8192
  OFF_CWPK = 16384,     // 4096  (16 frags x 64 lanes x uint4)
  OFF_KPF  = 20480,     // 256: comp0..2 = -2*kp, comp3 = |kp|^2 (A-frag k-order)
  OFF_SC1  = 20736, OFF_SH1 = 20864,
  OFF_SC2  = 20992, OFF_SH2 = 21120,
  OFF_SC3  = 21248, OFF_SH3 = 21376,
  OFF_RED  = 21504,     // 32*256 second-level partials
  OFF_CNT  = 29696,     // arrival counter (1 uint) + pad
  OFF_PART = 29952,     // up to 2048*256 f32 partials (all 3 BN stages)
  OFF_A    = 1078528,   // N*C floats
  OFF_B    = 1078528 + NPTS*NC,
};
// F (packed bf16 features, 4 MB) lives in d_out's feat section (dead until end).

struct KPArgs { float p[NK * 3]; };

// =================== host-side kernel-point computation ===================
static void host_make_kp(float* kp) {
  unsigned int mt[624];
  mt[0] = 42u;
  for (int i = 1; i < 624; ++i)
    mt[i] = 1812433253u * (mt[i-1] ^ (mt[i-1] >> 30)) + (unsigned)i;
  int pos = 624;
  auto next = [&]() -> unsigned int {
    if (pos == 624) {
      for (int i = 0; i < 624; ++i) {
        unsigned int y = (mt[i] & 0x80000000u) | (mt[(i+1)%624] & 0x7fffffffu);
        unsigned int v = mt[(i+397)%624] ^ (y >> 1);
        if (y & 1u) v ^= 0x9908b0dfu;
        mt[i] = v;
      }
      pos = 0;
    }
    unsigned int y = mt[pos++];
    y ^= y >> 11;
    y ^= (y << 7)  & 0x9d2c5680u;
    y ^= (y << 15) & 0xefc60000u;
    y ^= y >> 18;
    return y;
  };
  auto rdouble = [&]() -> double {
    unsigned int a = next() >> 5, b = next() >> 6;
    return ((double)a * 67108864.0 + (double)b) / 9007199254740992.0;
  };
  double gcache = 0.0; bool has_g = false;
  auto gauss = [&]() -> double {
    if (has_g) { has_g = false; return gcache; }
    double x1, x2, r2;
    do {
      x1 = 2.0 * rdouble() - 1.0;
      x2 = 2.0 * rdouble() - 1.0;
      r2 = x1*x1 + x2*x2;
    } while (r2 >= 1.0 || r2 == 0.0);
    double f = sqrt(-2.0 * log(r2) / r2);
    gcache = f * x1; has_g = true;
    return f * x2;
  };
  double g[126];
  for (int i = 0; i < 126; ++i) g[i] = gauss();
  kp[0] = 0.f; kp[1] = 0.f; kp[2] = 0.f;
  for (int r = 0; r < 14; ++r) {
    double x = g[r*3], y = g[r*3+1], z = g[r*3+2];
    double nrm = sqrt(x*x + y*y + z*z);
    kp[(1+r)*3+0] = (float)(x / nrm * 0.5);
    kp[(1+r)*3+1] = (float)(y / nrm * 0.5);
    kp[(1+r)*3+2] = (float)(z / nrm * 0.5);
  }
  for (int r = 0; r < 28; ++r) {
    double x = g[42+r*3], y = g[42+r*3+1], z = g[42+r*3+2];
    double nrm = sqrt(x*x + y*y + z*z);
    kp[(15+r)*3+0] = (float)(x / nrm);
    kp[(15+r)*3+1] = (float)(y / nrm);
    kp[(15+r)*3+2] = (float)(z / nrm);
  }
}

__device__ __forceinline__ unsigned short f2bf(float f) {   // RNE
  unsigned u = __float_as_uint(f);
  return (unsigned short)((u + 0x7FFFu + ((u >> 16) & 1u)) >> 16);
}
__device__ __forceinline__ unsigned pack_bf_trunc(float a, float b) {
  return __builtin_amdgcn_perm(__float_as_uint(b), __float_as_uint(a), 0x07060302);
}

// == prep: B-frag packs + kpf table + counter reset + coord/offset copy ====
__global__ __launch_bounds__(256) void prep_kernel(
    const float* __restrict__ w1, const float* __restrict__ w3,
    const float* __restrict__ cw, KPArgs kpa,
    const float* __restrict__ coord, const int* __restrict__ offs,
    uint4* __restrict__ w1pk, uint4* __restrict__ w3pk,
    uint4* __restrict__ cwpk, float* __restrict__ kpf,
    float* __restrict__ outdst, unsigned* __restrict__ cnt) {
  int idx = blockIdx.x * 256 + threadIdx.x;
  if (idx == 0) { *cnt = 0u; outdst[NPTS*3 + (size_t)NPTS*NC] = (float)offs[0]; }
  if (idx < 4096) {
    int mat = idx >> 11, t = idx & 2047;
    int f = t >> 6, l = t & 63;
    int nt = f >> 2, ks = f & 3;
    int c = nt*16 + (l & 15), k0 = ks*32 + (l >> 4)*8;
    const float* src = mat ? w3 : w1;
    const float* p = src + (size_t)c * NC + k0;
    uint4 q;
    q.x = (unsigned)f2bf(p[0]) | ((unsigned)f2bf(p[1]) << 16);
    q.y = (unsigned)f2bf(p[2]) | ((unsigned)f2bf(p[3]) << 16);
    q.z = (unsigned)f2bf(p[4]) | ((unsigned)f2bf(p[5]) << 16);
    q.w = (unsigned)f2bf(p[6]) | ((unsigned)f2bf(p[7]) << 16);
    (mat ? w3pk : w1pk)[f*64 + l] = q;
  } else if (idx < 4096 + 1024) {
    int t = idx - 4096;
    int f = t >> 6, l = t & 63;
    int ks = f >> 3, nt = f & 7;
    int c = nt*16 + (l & 15), k0 = ks*32 + (l >> 4)*8;
    float v[8];
    #pragma unroll
    for (int i = 0; i < 8; ++i) {
      int k = k0 + i;
      v[i] = (k < NK) ? cw[k*NC + c] : 0.f;
    }
    uint4 q;
    q.x = (unsigned)f2bf(v[0]) | ((unsigned)f2bf(v[1]) << 16);
    q.y = (unsigned)f2bf(v[2]) | ((unsigned)f2bf(v[3]) << 16);
    q.z = (unsigned)f2bf(v[4]) | ((unsigned)f2bf(v[5]) << 16);
    q.w = (unsigned)f2bf(v[6]) | ((unsigned)f2bf(v[7]) << 16);
    cwpk[f*64 + l] = q;
  } else if (idx < 4096 + 1024 + 256) {
    int t = idx - (4096 + 1024);
    int comp = t >> 6, slot = t & 63;
    int ks = slot >> 5, g = (slot >> 3) & 3, i = slot & 7;
    int k = ks*32 + g*8 + i;
    float val;
    if (k < NK) {
      float x = kpa.p[k*3+0], y = kpa.p[k*3+1], z = kpa.p[k*3+2];
      val = (comp == 0) ? -2.f*x : (comp == 1) ? -2.f*y : (comp == 2) ? -2.f*z
            : (x*x + y*y + z*z);
    } else {
      val = (comp == 3) ? 1e12f : 0.f;
    }
    kpf[comp*64 + slot] = val;
  } else {
    int t = idx - (4096 + 1024 + 256);          // coord copy as float4
    if (t < NPTS*3/4)
      ((float4*)outdst)[t] = ((const float4*)coord)[t];
  }
}

// ==== MFMA GEMM: 4 waves/block, W staged in LDS (B reads via lgkmcnt) =====
template<int BN, int PACK, int NSP>
__global__ __launch_bounds__(256) void gemm_mfma(
    const float* __restrict__ A, const uint4* __restrict__ Wpk,
    const float* __restrict__ sc, const float* __restrict__ sh,
    float* __restrict__ out, unsigned* __restrict__ Fpk,
    float* __restrict__ part) {
  constexpr int NFRAG = 32 / NSP;
  __shared__ uint4 w_l[NFRAG * 64];
  int tid = threadIdx.x;
  int half = (NSP == 1) ? 0 : (blockIdx.x & 1);
  int fragbase = half * 16;
  #pragma unroll
  for (int i = 0; i < NFRAG/4; ++i)
    w_l[i*256 + tid] = Wpk[fragbase*64 + i*256 + tid];
  __syncthreads();

  int l = tid & 63, wv = tid >> 6;
  int li = l & 15, g = l >> 4;
  int rt = ((NSP == 1) ? blockIdx.x : (blockIdx.x >> 1)) * 4 + wv;
  const float* arow = A + (size_t)(rt * 16 + li) * NC;

  short8 afr[4];
  #pragma unroll
  for (int ks = 0; ks < 4; ++ks) {
    int k0 = ks*32 + g*8;
    float4 a0 = *(const float4*)(arow + k0);
    float4 a1 = *(const float4*)(arow + k0 + 4);
    float v[8] = {a0.x,a0.y,a0.z,a0.w,a1.x,a1.y,a1.z,a1.w};
    if (BN) {
      float4 s0 = *(const float4*)(sc + k0), s1 = *(const float4*)(sc + k0 + 4);
      float4 h0 = *(const float4*)(sh + k0), h1 = *(const float4*)(sh + k0 + 4);
      float ss[8] = {s0.x,s0.y,s0.z,s0.w,s1.x,s1.y,s1.z,s1.w};
      float hh[8] = {h0.x,h0.y,h0.z,h0.w,h1.x,h1.y,h1.z,h1.w};
      #pragma unroll
      for (int i = 0; i < 8; ++i) v[i] = fmaxf(0.f, fmaf(v[i], ss[i], hh[i]));
    }
    union { unsigned q[4]; short8 s; } pk;
    #pragma unroll
    for (int p = 0; p < 4; ++p) pk.q[p] = pack_bf_trunc(v[2*p], v[2*p+1]);
    afr[ks] = pk.s;
  }

  constexpr int NT = 8 / NSP;
  f32x4 acc[NT];
  #pragma unroll
  for (int nt = 0; nt < NT; ++nt) acc[nt] = (f32x4){0.f,0.f,0.f,0.f};
  #pragma unroll
  for (int nt = 0; nt < NT; ++nt) {
    #pragma unroll
    for (int ks = 0; ks < 4; ++ks) {
      union { uint4 u; short8 s; } b;
      b.u = w_l[(nt*4 + ks)*64 + l];               // LDS (lgkmcnt only)
      acc[nt] = __builtin_amdgcn_mfma_f32_16x16x32_bf16(afr[ks], b.s, acc[nt], 0, 0, 0);
    }
  }

  if (PACK) {
    #pragma unroll
    for (int r = 0; r < 4; ++r) {
      uint4 q;
      q.x = pack_bf_trunc(acc[0][r], acc[4][r]);
      q.y = pack_bf_trunc(acc[1][r], acc[5][r]);
      q.z = pack_bf_trunc(acc[2][r], acc[6][r]);
      q.w = pack_bf_trunc(acc[3][r], acc[7][r]);
      ((uint4*)(Fpk + (size_t)(rt*16 + g*4 + r) * 64))[li] = q;
    }
  } else {
    #pragma unroll
    for (int nt = 0; nt < NT; ++nt)
      #pragma unroll
      for (int r = 0; r < 4; ++r)
        out[(size_t)(rt*16 + g*4 + r) * NC + (half*NT + nt)*16 + li] = acc[nt][r];
  }

  float s[NT], q[NT];
  #pragma unroll
  for (int nt = 0; nt < NT; ++nt) {
    float sv = acc[nt][0]+acc[nt][1]+acc[nt][2]+acc[nt][3];
    float qv = acc[nt][0]*acc[nt][0]+acc[nt][1]*acc[nt][1]
             + acc[nt][2]*acc[nt][2]+acc[nt][3]*acc[nt][3];
    sv += __shfl_xor(sv, 16); sv += __shfl_xor(sv, 32);
    qv += __shfl_xor(qv, 16); qv += __shfl_xor(qv, 32);
    s[nt] = sv; q[nt] = qv;
  }
  if (g == 0) {
    #pragma unroll
    for (int nt = 0; nt < NT; ++nt) {
      int c = (half*NT + nt)*16 + li;
      part[(size_t)rt*256 + c]       = s[nt];
      part[(size_t)rt*256 + 128 + c] = q[nt];
    }
  }
}

// ====== BN finalize: NBLK blocks, last-arriving block combines/finalizes ===
template<int NB, int NBLK>
__global__ __launch_bounds__(256) void bn_final_mb(
    const float* __restrict__ part,
    const float* __restrict__ g, const float* __restrict__ b,
    float* __restrict__ sc, float* __restrict__ sh,
    float* __restrict__ red, unsigned* __restrict__ cnt) {
  int t = threadIdx.x;
  int blk = blockIdx.x;
  constexpr int PER = NB / NBLK;
  size_t base = (size_t)blk * PER * 256 + t;
  float a0 = 0.f, a1 = 0.f, a2 = 0.f, a3 = 0.f;
  for (int i = 0; i < PER; i += 4) {
    a0 += part[base + (size_t)(i+0)*256];
    a1 += part[base + (size_t)(i+1)*256];
    a2 += part[base + (size_t)(i+2)*256];
    a3 += part[base + (size_t)(i+3)*256];
  }
  red[blk*256 + t] = (a0 + a1) + (a2 + a3);
  __threadfence();
  __shared__ unsigned lastv;
  if (t == 0) lastv = atomicAdd(cnt, 1u);
  __syncthreads();
  if (lastv == (unsigned)(NBLK - 1)) {
    __threadfence();
    float S = 0.f;
    #pragma unroll
    for (int k = 0; k < NBLK; ++k) S += red[k*256 + t];
    __shared__ float fs[256];
    fs[t] = S;
    __syncthreads();
    if (t < 128) {
      double mean = (double)fs[t] * (1.0 / (double)NPTS);
      double var  = (double)fs[128+t] * (1.0 / (double)NPTS) - mean * mean;
      double rstd = 1.0 / sqrt(var + 1e-5);
      double scale = (double)g[t] * rstd;
      sc[t] = (float)scale;
      sh[t] = (float)((double)b[t] - mean * scale);
    }
    if (t == 0) *cnt = 0u;
  }
}

// ==== KPConv: 8 pts/block (512 thr), LDS tables/B-frags, c&c accumulators ==
__global__ __launch_bounds__(512) void kpconv_kernel(
    const float* __restrict__ coord, const int* __restrict__ ref,
    const unsigned* __restrict__ F, const uint4* __restrict__ cwpk,
    const float* __restrict__ kpf,
    const float* __restrict__ sc1, const float* __restrict__ sh1,
    float* __restrict__ y, float* __restrict__ part)
{
  __shared__ uint4 cw_l[1024];      // all 16 B-frags (16 KB)
  __shared__ float kpf_l[256];
  __shared__ float bnt_l[256];      // sc1[0:128] | sh1[0:128]
  int tid = threadIdx.x;
  if (tid < 256) {
    kpf_l[tid] = kpf[tid];
    bnt_l[tid] = (tid < 128) ? sc1[tid] : sh1[tid - 128];
  }
  #pragma unroll
  for (int i = 0; i < 2; ++i) cw_l[i*512 + tid] = cwpk[i*512 + tid];
  __syncthreads();

  int l = tid & 63, w = tid >> 6;   // wave 0..7, 1 point/wave
  int g = l >> 4, li = l & 15;
  const uint4* F4 = (const uint4*)F;

  int n = blockIdx.x * 8 + w;
  const int* refrow = ref + (size_t)n * NH;

  int jr0 = refrow[li];
  int jr1 = refrow[16 + li];
  int jh0[4], jh1[4];
  #pragma unroll
  for (int r = 0; r < 4; ++r) { jh0[r] = refrow[g*4 + r]; jh1[r] = refrow[16 + g*4 + r]; }

  // coords BEFORE F gathers (vmcnt in-order)
  float cx = coord[n*3+0], cy = coord[n*3+1], cz = coord[n*3+2];
  bool s0r = ((unsigned)jr0 >= (unsigned)NPTS); int j0 = s0r ? 0 : jr0;
  bool s1r = ((unsigned)jr1 >= (unsigned)NPTS); int j1 = s1r ? 0 : jr1;
  float p0x = (s0r ? 1e6f : coord[j0*3+0]) - cx;
  float p0y = (s0r ? 1e6f : coord[j0*3+1]) - cy;
  float p0z = (s0r ? 1e6f : coord[j0*3+2]) - cz;
  float p1x = (s1r ? 1e6f : coord[j1*3+0]) - cx;
  float p1y = (s1r ? 1e6f : coord[j1*3+1]) - cy;
  float p1z = (s1r ? 1e6f : coord[j1*3+2]) - cz;

  // F gathers LAST in the vmcnt queue — in flight through influence + MFMA
  uint4 fqA[4], fqB[4];
  #pragma unroll
  for (int r = 0; r < 4; ++r) {
    int jhc = ((unsigned)jh0[r] >= (unsigned)NPTS) ? 0 : jh0[r];
    fqA[r] = F4[(size_t)jhc * 16 + li];
  }
  #pragma unroll
  for (int r = 0; r < 4; ++r) {
    int jhc = ((unsigned)jh1[r] >= (unsigned)NPTS) ? 0 : jh1[r];
    fqB[r] = F4[(size_t)jhc * 16 + li];
  }

  float pp0 = fmaf(p0z, p0z, fmaf(p0y, p0y, p0x*p0x));
  float pp1 = fmaf(p1z, p1z, fmaf(p1y, p1y, p1x*p1x));

  short8 afr[2][2];   // [mt][ks]
  #pragma unroll
  for (int ks = 0; ks < 2; ++ks) {
    const float* kb = kpf_l + ks*32 + g*8;       // LDS
    float4 X0 = *(const float4*)(kb +   0), X1 = *(const float4*)(kb +   4);
    float4 Y0 = *(const float4*)(kb +  64), Y1 = *(const float4*)(kb +  68);
    float4 Z0 = *(const float4*)(kb + 128), Z1 = *(const float4*)(kb + 132);
    float4 K0 = *(const float4*)(kb + 192), K1 = *(const float4*)(kb + 196);
    float X[8] = {X0.x,X0.y,X0.z,X0.w,X1.x,X1.y,X1.z,X1.w};
    float Y[8] = {Y0.x,Y0.y,Y0.z,Y0.w,Y1.x,Y1.y,Y1.z,Y1.w};
    float Z[8] = {Z0.x,Z0.y,Z0.z,Z0.w,Z1.x,Z1.y,Z1.z,Z1.w};
    float K[8] = {K0.x,K0.y,K0.z,K0.w,K1.x,K1.y,K1.z,K1.w};
    #pragma unroll
    for (int mt = 0; mt < 2; ++mt) {
      float fx = mt ? p1x : p0x, fy = mt ? p1y : p0y, fz = mt ? p1z : p0z;
      float fp = mt ? pp1 : pp0;
      unsigned u[8];
      #pragma unroll
      for (int i = 0; i < 8; ++i) {
        float d2 = fmaf(fz, Z[i], fmaf(fy, Y[i], fmaf(fx, X[i], fp + K[i])));
        d2 = fmaxf(d2, 0.f);
        float iv = fmaxf(1.f - __builtin_amdgcn_sqrtf(d2), 0.f);
        u[i] = __float_as_uint(iv);
      }
      union { unsigned q[4]; short8 s; } pk;
      #pragma unroll
      for (int p = 0; p < 4; ++p)
        pk.q[p] = __builtin_amdgcn_perm(u[2*p+1], u[2*p], 0x07060302);
      afr[mt][ks] = pk.s;
    }
  }

  // BN1 tables from LDS (broadcast reads)
  float s1[8], h1[8];
  #pragma unroll
  for (int p = 0; p < 8; ++p) { s1[p] = bnt_l[p*16 + li]; h1[p] = bnt_l[128 + p*16 + li]; }

  // compute-and-consume accumulators (live acc = one f32x4)
  float outp[8];
  #pragma unroll
  for (int p = 0; p < 8; ++p) outp[p] = 0.f;

  #pragma unroll
  for (int nt = 0; nt < 8; ++nt) {
    union { uint4 u; short8 s; } b0, b1;
    b0.u = cw_l[(0*8 + nt)*64 + l];
    b1.u = cw_l[(1*8 + nt)*64 + l];
    #pragma unroll
    for (int mt = 0; mt < 2; ++mt) {
      f32x4 a = (f32x4){0.f, 0.f, 0.f, 0.f};
      a = __builtin_amdgcn_mfma_f32_16x16x32_bf16(afr[mt][0], b0.s, a, 0, 0, 0);
      a = __builtin_amdgcn_mfma_f32_16x16x32_bf16(afr[mt][1], b1.s, a, 0, 0, 0);
      #pragma unroll
      for (int r = 0; r < 4; ++r) {
        uint4 q = mt ? fqB[r] : fqA[r];
        unsigned uu = (nt & 3) == 0 ? q.x : (nt & 3) == 1 ? q.y
                    : (nt & 3) == 2 ? q.z : q.w;
        float f = (nt < 4) ? __uint_as_float(uu << 16)
                           : __uint_as_float(uu & 0xffff0000u);
        f = fmaxf(0.f, fmaf(f, s1[nt], h1[nt]));
        outp[nt] = fmaf(a[r], f, outp[nt]);
      }
    }
  }

  #pragma unroll
  for (int p = 0; p < 8; ++p) {
    outp[p] += __shfl_xor(outp[p], 16);
    outp[p] += __shfl_xor(outp[p], 32);
  }
  float o0 = (g == 0) ? outp[0] : (g == 1) ? outp[1] : (g == 2) ? outp[2] : outp[3];
  float o1 = (g == 0) ? outp[4] : (g == 1) ? outp[5] : (g == 2) ? outp[6] : outp[7];
  y[(size_t)n * NC + l]      = o0;
  y[(size_t)n * NC + 64 + l] = o1;

  // fused BN2 stats across the block's 8 points
  __shared__ float sl[8][128], ql[8][128];
  sl[w][l] = o0; sl[w][64 + l] = o1;
  ql[w][l] = o0 * o0; ql[w][64 + l] = o1 * o1;
  __syncthreads();
  if (tid < 256) {
    int c = tid & 127;
    const float (*src)[128] = (tid < 128) ? sl : ql;
    float v0 = 0.f, v1 = 0.f;
    #pragma unroll
    for (int k = 0; k < 8; k += 2) { v0 += src[k][c]; v1 += src[k+1][c]; }
    part[(size_t)blockIdx.x*256 + tid] = v0 + v1;
  }
}

// ====== final: out.feat = relu(identity + z*sc + sh) (coord/offset in prep) =
__global__ __launch_bounds__(256) void final_out_kernel(
    const float* __restrict__ feat, const float* __restrict__ z,
    const float* __restrict__ sc, const float* __restrict__ sh,
    float* __restrict__ out) {
  int i = blockIdx.x * 256 + threadIdx.x;
  float4 f = ((const float4*)feat)[i];
  float4 v = ((const float4*)z)[i];
  int c = (i & 31) << 2;
  v.x = fmaxf(0.f, f.x + fmaf(v.x, sc[c+0], sh[c+0]));
  v.y = fmaxf(0.f, f.y + fmaf(v.y, sc[c+1], sh[c+1]));
  v.z = fmaxf(0.f, f.z + fmaf(v.z, sc[c+2], sh[c+2]));
  v.w = fmaxf(0.f, f.w + fmaf(v.w, sc[c+3], sh[c+3]));
  ((float4*)out)[NPTS*3/4 + i] = v;
}

// =========================================================================
extern "C" void kernel_launch(void* const* d_in, const int* in_sizes, int n_in,
                              void* d_out, int out_size, void* d_ws, size_t ws_size,
                              hipStream_t stream) {
  (void)in_sizes; (void)n_in; (void)out_size; (void)ws_size;
  const float* coord = (const float*)d_in[0];
  const float* feat  = (const float*)d_in[1];
  const int*   offs  = (const int*)d_in[2];
  const int*   ref   = (const int*)d_in[3];
  const float* w1    = (const float*)d_in[4];
  const float* w3    = (const float*)d_in[5];
  const float* cw    = (const float*)d_in[6];
  const float* g1 = (const float*)d_in[7],  *b1 = (const float*)d_in[8];
  const float* g2 = (const float*)d_in[9],  *b2 = (const float*)d_in[10];
  const float* g3 = (const float*)d_in[11], *b3 = (const float*)d_in[12];

  float* ws  = (float*)d_ws;
  float* out = (float*)d_out;
  uint4* w1pk = (uint4*)(ws + OFF_W1PK);
  uint4* w3pk = (uint4*)(ws + OFF_W3PK);
  uint4* cwpk = (uint4*)(ws + OFF_CWPK);
  float* kpf  = ws + OFF_KPF;
  float* sc1 = ws + OFF_SC1, *sh1 = ws + OFF_SH1;
  float* sc2 = ws + OFF_SC2, *sh2 = ws + OFF_SH2;
  float* sc3 = ws + OFF_SC3, *sh3 = ws + OFF_SH3;
  float* red  = ws + OFF_RED;
  unsigned* cnt = (unsigned*)(ws + OFF_CNT);
  float* part = ws + OFF_PART;
  float* A = ws + OFF_A;
  float* B = ws + OFF_B;
  unsigned* F = (unsigned*)(out + NPTS*3);

  KPArgs kpa;
  host_make_kp(kpa.p);

  // prep: packs + kpf + cnt + out.coord/offset
  prep_kernel<<<(4096 + 1024 + 256 + NPTS*3/4 + 255)/256, 256, 0, stream>>>(
      w1, w3, cw, kpa, coord, offs, w1pk, w3pk, cwpk, kpf, out, cnt);

  // fc1 (MFMA, 4 waves/block, W in LDS, writes packed F, stats fused)
  gemm_mfma<0,1,1><<<NPTS/64, 256, 0, stream>>>(feat, w1pk, nullptr, nullptr,
                                                nullptr, F, part);
  bn_final_mb<1024, 16><<<16, 256, 0, stream>>>(part, g1, b1, sc1, sh1, red, cnt);

  // KPConv (8 pts/block, LDS tables + B-frags, BN1 inline, BN2 stats fused)
  kpconv_kernel<<<NPTS/8, 512, 0, stream>>>(coord, ref, F, cwpk, kpf,
                                            sc1, sh1, B, part);
  bn_final_mb<2048, 32><<<32, 256, 0, stream>>>(part, g2, b2, sc2, sh2, red, cnt);

  // fc3 (MFMA, 4 waves/block, W-half in LDS, BN2-apply fused, stats fused)
  gemm_mfma<1,0,2><<<NPTS/32, 256, 0, stream>>>(B, w3pk, sc2, sh2, A, nullptr, part);
  bn_final_mb<1024, 16><<<16, 256, 0, stream>>>(part, g3, b3, sc3, sh3, red, cnt);

  // residual + ReLU (feat section only)
  final_out_kernel<<<NPTS*NC/4/256, 256, 0, stream>>>(feat, A, sc3, sh3, out);
}